// Round 4
// baseline (914.178 us; speedup 1.0000x reference)
//
#include <hip/hip_runtime.h>
#include <hip/hip_bf16.h>

#define DOUT 64
#define DIN 128
#define NEG_SLOPE 0.2f
#define EPSV 1e-10f
#define LDA 136        // 128 + 8 bf16 pad
#define BKT_SHIFT 8    // 256 targets per bucket -> one agg block per bucket
#define BKT_SIZE 256
#define NBMAX 512      // compile-time bucket-array bound (runtime nbk=391)
#define PASSA_CHUNK 2048
#define CAP 12         // staging slots per bucket per block: 48 KB
#define CAP_B 5120     // per-bucket global region (mean 4096, sd ~64: +16 sigma)
#define ASTRIDE 65     // LDS accumulator row stride (bank-randomizing)
#define AGT 512        // threads in aggregate kernel
#define BATCH 8        // records in flight per 8-lane group (MLP)

typedef __attribute__((ext_vector_type(8))) __bf16 bf16x8;
typedef __attribute__((ext_vector_type(8))) unsigned short ushortx8;
typedef __attribute__((ext_vector_type(4))) float floatx4;

__device__ __forceinline__ float bf16_to_f32(unsigned short u) {
    return __uint_as_float(((unsigned int)u) << 16);
}
__device__ __forceinline__ unsigned short f32_to_bf16(float f) {
    __hip_bfloat16 h = __float2bfloat16(f);
    unsigned short u;
    __builtin_memcpy(&u, &h, 2);
    return u;
}
__device__ __forceinline__ unsigned int f32x2_to_bf16x2(float a, float b) {
    __hip_bfloat162 h = __float22bfloat162_rn(make_float2(a, b));
    unsigned int u;
    __builtin_memcpy(&u, &h, 4);
    return u;
}
__device__ __forceinline__ float leaky_exp(float vs, float vt, float w) {
    float v = vs + vt;
    v = (v > 0.f) ? v : NEG_SLOPE * v;
    return __expf(v * w);
}

// ---------------------------------------------------------------------------
// Kernel 1: Wh = x @ W via bf16 MFMA; fused s_src, s_tgt. Wh stored bf16.
// ---------------------------------------------------------------------------
__global__ __launch_bounds__(256) void gat_gemm_scores(
    const float* __restrict__ x, const float* __restrict__ W,
    const float* __restrict__ a, unsigned short* __restrict__ Wh,
    float* __restrict__ ssrc, float* __restrict__ stgt, int N)
{
    __shared__ unsigned short A_sh[64 * LDA];
    __shared__ unsigned short B_sh[64 * LDA];

    const int tid = threadIdx.x;
    const int rowbase = blockIdx.x * 64;

    for (int idx = tid; idx < DIN * DOUT; idx += 256) {
        int k = idx >> 6, n = idx & 63;
        B_sh[n * LDA + k] = f32_to_bf16(W[idx]);
    }
    for (int it = 0; it < 8; ++it) {
        int flat = it * 1024 + tid * 4;
        int row = flat >> 7, k = flat & 127;
        int grow = rowbase + row;
        float4 v = make_float4(0.f, 0.f, 0.f, 0.f);
        if (grow < N) v = *(const float4*)&x[(size_t)grow * DIN + k];
        uint2 packed = make_uint2(f32x2_to_bf16x2(v.x, v.y),
                                  f32x2_to_bf16x2(v.z, v.w));
        *(uint2*)&A_sh[row * LDA + k] = packed;
    }
    __syncthreads();

    const int lane = tid & 63;
    const int wv   = tid >> 6;
    const int c16  = lane & 15;
    const int quad = lane >> 4;

    floatx4 acc[4] = {floatx4{0,0,0,0}, floatx4{0,0,0,0},
                      floatx4{0,0,0,0}, floatx4{0,0,0,0}};

    const int arow = (wv * 16 + c16) * LDA;
    #pragma unroll
    for (int kk = 0; kk < 4; ++kk) {
        const int koff = kk * 32 + quad * 8;
        bf16x8 af = __builtin_bit_cast(bf16x8, *(const ushortx8*)&A_sh[arow + koff]);
        #pragma unroll
        for (int nt = 0; nt < 4; ++nt) {
            bf16x8 bf = __builtin_bit_cast(bf16x8,
                           *(const ushortx8*)&B_sh[(nt * 16 + c16) * LDA + koff]);
            acc[nt] = __builtin_amdgcn_mfma_f32_16x16x32_bf16(af, bf, acc[nt], 0, 0, 0);
        }
    }

    float asrc_v[4], atgt_v[4];
    #pragma unroll
    for (int nt = 0; nt < 4; ++nt) {
        asrc_v[nt] = a[nt * 16 + c16];
        atgt_v[nt] = a[64 + nt * 16 + c16];
    }
    const int rbase = rowbase + wv * 16 + quad * 4;
    #pragma unroll
    for (int r = 0; r < 4; ++r) {
        int row = rbase + r;
        if (row < N) {
            #pragma unroll
            for (int nt = 0; nt < 4; ++nt)
                Wh[(size_t)row * DOUT + nt * 16 + c16] = f32_to_bf16(acc[nt][r]);
        }
    }
    #pragma unroll
    for (int r = 0; r < 4; ++r) {
        float ps = 0.f, pt = 0.f;
        #pragma unroll
        for (int nt = 0; nt < 4; ++nt) {
            ps += acc[nt][r] * asrc_v[nt];
            pt += acc[nt][r] * atgt_v[nt];
        }
        #pragma unroll
        for (int m = 1; m < 16; m <<= 1) {
            ps += __shfl_xor(ps, m);
            pt += __shfl_xor(pt, m);
        }
        if (c16 == 0) {
            int row = rbase + r;
            if (row < N) { ssrc[row] = ps; stgt[row] = pt; }
        }
    }
}

// ---------------------------------------------------------------------------
// Kernel 2 (fused): edge logits + bucket scatter in ONE pass over ei.
// ---------------------------------------------------------------------------
__global__ __launch_bounds__(256) void gat_bin_fused(
    const int* __restrict__ ei, const float* __restrict__ ew,
    const float* __restrict__ ssrc, const float* __restrict__ stgt,
    int* __restrict__ cnt, int2* __restrict__ staged_g, int E)
{
    __shared__ int2 staged[NBMAX * CAP];   // 48 KB
    __shared__ int fill[NBMAX];            // 2 KB
    __shared__ int gpos[NBMAX];            // 2 KB
    const int tid = threadIdx.x;
    for (int bb = tid; bb < NBMAX; bb += 256) fill[bb] = 0;
    __syncthreads();

    const int base = blockIdx.x * PASSA_CHUNK;
    #pragma unroll
    for (int j = 0; j < PASSA_CHUNK / 1024; ++j) {
        int e4 = base + j * 1024 + tid * 4;
        if (e4 + 3 < E) {
            int4 ss = *(const int4*)&ei[e4];
            int4 tt = *(const int4*)&ei[E + e4];
            float4 ww = *(const float4*)&ew[e4];
            float vs0 = ssrc[ss.x], vs1 = ssrc[ss.y], vs2 = ssrc[ss.z], vs3 = ssrc[ss.w];
            float vt0 = stgt[tt.x], vt1 = stgt[tt.y], vt2 = stgt[tt.z], vt3 = stgt[tt.w];
            float pv[4] = {leaky_exp(vs0, vt0, ww.x), leaky_exp(vs1, vt1, ww.y),
                           leaky_exp(vs2, vt2, ww.z), leaky_exp(vs3, vt3, ww.w)};
            int sv[4] = {ss.x, ss.y, ss.z, ss.w};
            int tv[4] = {tt.x, tt.y, tt.z, tt.w};
            #pragma unroll
            for (int u = 0; u < 4; ++u) {
                int b = tv[u] >> BKT_SHIFT;
                int2 rec = make_int2(sv[u] | ((tv[u] & (BKT_SIZE - 1)) << 17),
                                     __float_as_int(pv[u]));
                int pos = atomicAdd(&fill[b], 1);
                if (pos < CAP) staged[b * CAP + pos] = rec;
                else {
                    int gp = atomicAdd(&cnt[b], 1);
                    if (gp < CAP_B) staged_g[(size_t)b * CAP_B + gp] = rec;
                }
            }
        } else {
            for (int e = e4; e < E; ++e) {
                int s = ei[e], t = ei[E + e];
                float p = leaky_exp(ssrc[s], stgt[t], ew[e]);
                int b = t >> BKT_SHIFT;
                int2 rec = make_int2(s | ((t & (BKT_SIZE - 1)) << 17),
                                     __float_as_int(p));
                int pos = atomicAdd(&fill[b], 1);
                if (pos < CAP) staged[b * CAP + pos] = rec;
                else {
                    int gp = atomicAdd(&cnt[b], 1);
                    if (gp < CAP_B) staged_g[(size_t)b * CAP_B + gp] = rec;
                }
            }
        }
    }
    __syncthreads();

    for (int bb = tid; bb < NBMAX; bb += 256) {
        int f = min(fill[bb], CAP);
        gpos[bb] = (f > 0) ? atomicAdd(&cnt[bb], f) : 0;
    }
    __syncthreads();

    for (int i = tid; i < NBMAX * CAP; i += 256) {
        int b = i / CAP;
        int r = i - b * CAP;
        if (r < min(fill[b], CAP)) {
            int gp = gpos[b] + r;
            if (gp < CAP_B) staged_g[(size_t)b * CAP_B + gp] = staged[i];
        }
    }
}

// ---------------------------------------------------------------------------
// Kernel 3: bucket aggregation with LDS float accumulators.
// Intrinsic atomicAdd on __shared__ (correct waitcnt ordering, proven in R2)
// + BATCH=8 latency-hiding pipeline + one block per 256-target bucket.
// ---------------------------------------------------------------------------
__global__ __launch_bounds__(AGT, 4) void gat_bucket_agg(
    const int2* __restrict__ staged_g, const int* __restrict__ cnt,
    const unsigned short* __restrict__ Wh, float* __restrict__ out, int N)
{
    __shared__ float accbuf[BKT_SIZE * ASTRIDE];   // 66,560 B
    __shared__ float psum[BKT_SIZE];               // 1 KB

    const int b = blockIdx.x;
    const int tid = threadIdx.x;

    for (int i = tid; i < BKT_SIZE * ASTRIDE; i += AGT) accbuf[i] = 0.f;
    if (tid < BKT_SIZE) psum[tid] = 0.f;
    __syncthreads();

    const int n = min(cnt[b], CAP_B);
    const size_t bbase = (size_t)b * CAP_B;
    const int grp = tid >> 3;          // 0..63
    const int c8  = tid & 7;           // channel block: c8*8 .. c8*8+7
    const int NG  = AGT / 8;           // 64 groups
    const int nm1 = n - 1;

    if (n > 0) {
        for (int i0 = grp; i0 < n; i0 += BATCH * NG) {
            int2 r[BATCH];
            #pragma unroll
            for (int u = 0; u < BATCH; ++u) {
                int idx = i0 + u * NG;
                r[u] = staged_g[bbase + min(idx, nm1)];   // branchless, in-bounds
            }
            int tl[BATCH];
            float pv[BATCH];
            ushortx8 w[BATCH];
            #pragma unroll
            for (int u = 0; u < BATCH; ++u) {
                int idx = i0 + u * NG;
                int s = r[u].x & 0x1FFFF;
                tl[u] = (r[u].x >> 17) & (BKT_SIZE - 1);
                pv[u] = (idx <= nm1) ? __int_as_float(r[u].y) : 0.f;  // tail adds 0
                w[u] = *(const ushortx8*)&Wh[(size_t)s * DOUT + c8 * 8];
            }
            #pragma unroll
            for (int u = 0; u < BATCH; ++u) {
                float* ap = &accbuf[tl[u] * ASTRIDE + c8 * 8];
                #pragma unroll
                for (int j = 0; j < 8; ++j)
                    atomicAdd(&ap[j], pv[u] * bf16_to_f32(w[u][j]));
                if (c8 == 0) atomicAdd(&psum[tl[u]], pv[u]);
            }
        }
    }
    __syncthreads();

    if (tid < BKT_SIZE) psum[tid] = 1.0f / (psum[tid] + EPSV);
    __syncthreads();

    const int tbase = b << BKT_SHIFT;
    for (int idx = tid; idx < BKT_SIZE * 16; idx += AGT) {
        int tl = idx >> 4;
        int c4 = (idx & 15) << 2;
        int g = tbase + tl;
        if (g < N) {
            float inv = psum[tl];
            const float* ab = &accbuf[tl * ASTRIDE + c4];
            float4 o = make_float4(ab[0] * inv, ab[1] * inv,
                                   ab[2] * inv, ab[3] * inv);
            *(float4*)&out[(size_t)g * DOUT + c4] = o;
        }
    }
}

extern "C" void kernel_launch(void* const* d_in, const int* in_sizes, int n_in,
                              void* d_out, int out_size, void* d_ws, size_t ws_size,
                              hipStream_t stream) {
    const float* x  = (const float*)d_in[0];
    const int*   ei = (const int*)d_in[1];
    const float* ew = (const float*)d_in[2];
    const float* W  = (const float*)d_in[3];
    const float* a  = (const float*)d_in[4];
    const int N = in_sizes[0] / DIN;
    const int E = in_sizes[2];
    float* out = (float*)d_out;

    const int nbk = (N + BKT_SIZE - 1) >> BKT_SHIFT;   // 391

    char* wsb = (char*)d_ws;
    unsigned short* Wh = (unsigned short*)wsb;      wsb += (size_t)N * DOUT * 2;
    float* ssrc      = (float*)wsb;                 wsb += (size_t)N * 4;
    float* stgt      = (float*)wsb;                 wsb += (size_t)N * 4;
    int*   cnt       = (int*)wsb;                   wsb += NBMAX * 4;
    wsb = (char*)(((uintptr_t)wsb + 15) & ~(uintptr_t)15);
    int2*  staged_g  = (int2*)wsb;                  wsb += (size_t)nbk * CAP_B * 8;

    (void)hipMemsetAsync(cnt, 0, NBMAX * sizeof(int), stream);

    gat_gemm_scores<<<(N + 63) / 64, 256, 0, stream>>>(x, W, a, Wh, ssrc, stgt, N);
    gat_bin_fused<<<(E + PASSA_CHUNK - 1) / PASSA_CHUNK, 256, 0, stream>>>(
                  ei, ew, ssrc, stgt, cnt, staged_g, E);
    gat_bucket_agg<<<nbk, AGT, 0, stream>>>(staged_g, cnt, Wh, out, N);
}

// Round 5
// 212.113 us; speedup vs baseline: 4.3099x; 4.3099x over previous
//
#include <hip/hip_runtime.h>
#include <hip/hip_bf16.h>

#define DOUT 64
#define DIN 128
#define NEG_SLOPE 0.2f
#define EPSV 1e-10f
#define LDA 136        // 128 + 8 bf16 pad
#define BKT_SHIFT 8    // 256 targets per bucket
#define BKT_SIZE 256
#define NBMAX 512      // compile-time bucket-array bound (runtime nbk=391)
#define PASSA_CHUNK 2048
#define CAP 12         // staging slots per bucket per block: 48 KB
#define CAP_B 5120     // per-bucket region (mean 4096, sd ~64: +16 sigma)

typedef __attribute__((ext_vector_type(8))) __bf16 bf16x8;
typedef __attribute__((ext_vector_type(8))) unsigned short ushortx8;
typedef __attribute__((ext_vector_type(4))) float floatx4;

__device__ __forceinline__ float bf16_to_f32(unsigned short u) {
    return __uint_as_float(((unsigned int)u) << 16);
}
__device__ __forceinline__ unsigned short f32_to_bf16(float f) {
    __hip_bfloat16 h = __float2bfloat16(f);
    unsigned short u;
    __builtin_memcpy(&u, &h, 2);
    return u;
}
__device__ __forceinline__ unsigned int f32x2_to_bf16x2(float a, float b) {
    __hip_bfloat162 h = __float22bfloat162_rn(make_float2(a, b));
    unsigned int u;
    __builtin_memcpy(&u, &h, 4);
    return u;
}
__device__ __forceinline__ float leaky_exp(float vs, float vt, float w) {
    float v = vs + vt;
    v = (v > 0.f) ? v : NEG_SLOPE * v;
    return __expf(v * w);
}

// ---------------------------------------------------------------------------
// Kernel 1: Wh = x @ W via bf16 MFMA; fused s_src, s_tgt. Wh stored bf16.
// (unchanged, proven)
// ---------------------------------------------------------------------------
__global__ __launch_bounds__(256) void gat_gemm_scores(
    const float* __restrict__ x, const float* __restrict__ W,
    const float* __restrict__ a, unsigned short* __restrict__ Wh,
    float* __restrict__ ssrc, float* __restrict__ stgt, int N)
{
    __shared__ unsigned short A_sh[64 * LDA];
    __shared__ unsigned short B_sh[64 * LDA];

    const int tid = threadIdx.x;
    const int rowbase = blockIdx.x * 64;

    for (int idx = tid; idx < DIN * DOUT; idx += 256) {
        int k = idx >> 6, n = idx & 63;
        B_sh[n * LDA + k] = f32_to_bf16(W[idx]);
    }
    for (int it = 0; it < 8; ++it) {
        int flat = it * 1024 + tid * 4;
        int row = flat >> 7, k = flat & 127;
        int grow = rowbase + row;
        float4 v = make_float4(0.f, 0.f, 0.f, 0.f);
        if (grow < N) v = *(const float4*)&x[(size_t)grow * DIN + k];
        uint2 packed = make_uint2(f32x2_to_bf16x2(v.x, v.y),
                                  f32x2_to_bf16x2(v.z, v.w));
        *(uint2*)&A_sh[row * LDA + k] = packed;
    }
    __syncthreads();

    const int lane = tid & 63;
    const int wv   = tid >> 6;
    const int c16  = lane & 15;
    const int quad = lane >> 4;

    floatx4 acc[4] = {floatx4{0,0,0,0}, floatx4{0,0,0,0},
                      floatx4{0,0,0,0}, floatx4{0,0,0,0}};

    const int arow = (wv * 16 + c16) * LDA;
    #pragma unroll
    for (int kk = 0; kk < 4; ++kk) {
        const int koff = kk * 32 + quad * 8;
        bf16x8 af = __builtin_bit_cast(bf16x8, *(const ushortx8*)&A_sh[arow + koff]);
        #pragma unroll
        for (int nt = 0; nt < 4; ++nt) {
            bf16x8 bf = __builtin_bit_cast(bf16x8,
                           *(const ushortx8*)&B_sh[(nt * 16 + c16) * LDA + koff]);
            acc[nt] = __builtin_amdgcn_mfma_f32_16x16x32_bf16(af, bf, acc[nt], 0, 0, 0);
        }
    }

    float asrc_v[4], atgt_v[4];
    #pragma unroll
    for (int nt = 0; nt < 4; ++nt) {
        asrc_v[nt] = a[nt * 16 + c16];
        atgt_v[nt] = a[64 + nt * 16 + c16];
    }
    const int rbase = rowbase + wv * 16 + quad * 4;
    #pragma unroll
    for (int r = 0; r < 4; ++r) {
        int row = rbase + r;
        if (row < N) {
            #pragma unroll
            for (int nt = 0; nt < 4; ++nt)
                Wh[(size_t)row * DOUT + nt * 16 + c16] = f32_to_bf16(acc[nt][r]);
        }
    }
    #pragma unroll
    for (int r = 0; r < 4; ++r) {
        float ps = 0.f, pt = 0.f;
        #pragma unroll
        for (int nt = 0; nt < 4; ++nt) {
            ps += acc[nt][r] * asrc_v[nt];
            pt += acc[nt][r] * atgt_v[nt];
        }
        #pragma unroll
        for (int m = 1; m < 16; m <<= 1) {
            ps += __shfl_xor(ps, m);
            pt += __shfl_xor(pt, m);
        }
        if (c16 == 0) {
            int row = rbase + r;
            if (row < N) { ssrc[row] = ps; stgt[row] = pt; }
        }
    }
}

// ---------------------------------------------------------------------------
// Kernel 2 (fused): edge logits + bucket scatter in ONE pass over ei.
// (unchanged from R4, passing)
// ---------------------------------------------------------------------------
__global__ __launch_bounds__(256) void gat_bin_fused(
    const int* __restrict__ ei, const float* __restrict__ ew,
    const float* __restrict__ ssrc, const float* __restrict__ stgt,
    int* __restrict__ cnt, int2* __restrict__ staged_g, int E)
{
    __shared__ int2 staged[NBMAX * CAP];   // 48 KB
    __shared__ int fill[NBMAX];            // 2 KB
    __shared__ int gpos[NBMAX];            // 2 KB
    const int tid = threadIdx.x;
    for (int bb = tid; bb < NBMAX; bb += 256) fill[bb] = 0;
    __syncthreads();

    const int base = blockIdx.x * PASSA_CHUNK;
    #pragma unroll
    for (int j = 0; j < PASSA_CHUNK / 1024; ++j) {
        int e4 = base + j * 1024 + tid * 4;
        if (e4 + 3 < E) {
            int4 ss = *(const int4*)&ei[e4];
            int4 tt = *(const int4*)&ei[E + e4];
            float4 ww = *(const float4*)&ew[e4];
            float vs0 = ssrc[ss.x], vs1 = ssrc[ss.y], vs2 = ssrc[ss.z], vs3 = ssrc[ss.w];
            float vt0 = stgt[tt.x], vt1 = stgt[tt.y], vt2 = stgt[tt.z], vt3 = stgt[tt.w];
            float pv[4] = {leaky_exp(vs0, vt0, ww.x), leaky_exp(vs1, vt1, ww.y),
                           leaky_exp(vs2, vt2, ww.z), leaky_exp(vs3, vt3, ww.w)};
            int sv[4] = {ss.x, ss.y, ss.z, ss.w};
            int tv[4] = {tt.x, tt.y, tt.z, tt.w};
            #pragma unroll
            for (int u = 0; u < 4; ++u) {
                int b = tv[u] >> BKT_SHIFT;
                int2 rec = make_int2(sv[u] | ((tv[u] & (BKT_SIZE - 1)) << 17),
                                     __float_as_int(pv[u]));
                int pos = atomicAdd(&fill[b], 1);
                if (pos < CAP) staged[b * CAP + pos] = rec;
                else {
                    int gp = atomicAdd(&cnt[b], 1);
                    if (gp < CAP_B) staged_g[(size_t)b * CAP_B + gp] = rec;
                }
            }
        } else {
            for (int e = e4; e < E; ++e) {
                int s = ei[e], t = ei[E + e];
                float p = leaky_exp(ssrc[s], stgt[t], ew[e]);
                int b = t >> BKT_SHIFT;
                int2 rec = make_int2(s | ((t & (BKT_SIZE - 1)) << 17),
                                     __float_as_int(p));
                int pos = atomicAdd(&fill[b], 1);
                if (pos < CAP) staged[b * CAP + pos] = rec;
                else {
                    int gp = atomicAdd(&cnt[b], 1);
                    if (gp < CAP_B) staged_g[(size_t)b * CAP_B + gp] = rec;
                }
            }
        }
    }
    __syncthreads();

    for (int bb = tid; bb < NBMAX; bb += 256) {
        int f = min(fill[bb], CAP);
        gpos[bb] = (f > 0) ? atomicAdd(&cnt[bb], f) : 0;
    }
    __syncthreads();

    for (int i = tid; i < NBMAX * CAP; i += 256) {
        int b = i / CAP;
        int r = i - b * CAP;
        if (r < min(fill[b], CAP)) {
            int gp = gpos[b] + r;
            if (gp < CAP_B) staged_g[(size_t)b * CAP_B + gp] = staged[i];
        }
    }
}

// ---------------------------------------------------------------------------
// Kernel 3 (new): per-bucket fine counting sort, all in LDS. Streams the
// bucket's records (coalesced) twice, writes sorted segments (coalesced) plus
// per-target [rbeg,rend). 391 blocks is fine HERE because access is
// streaming, not random-gather (R4 post-mortem: the low-block-count latency
// wall only bites on dependent random gathers).
// ---------------------------------------------------------------------------
__global__ __launch_bounds__(256) void gat_binB_sort(
    const int2* __restrict__ staged_g, const int* __restrict__ cnt,
    int* __restrict__ rbeg, int* __restrict__ rend,
    int2* __restrict__ sorted_sp, int N)
{
    __shared__ int lcnt[BKT_SIZE];
    __shared__ int lcur[BKT_SIZE];
    __shared__ int lscan[BKT_SIZE];

    const int b = blockIdx.x;
    const int tid = threadIdx.x;
    const int base = b * CAP_B;
    const int n = min(cnt[b], CAP_B);

    lcnt[tid] = 0;
    __syncthreads();

    for (int i = tid; i < n; i += 256)
        atomicAdd(&lcnt[(staged_g[base + i].x >> 17) & (BKT_SIZE - 1)], 1);
    __syncthreads();

    int c = lcnt[tid];
    lscan[tid] = c;
    __syncthreads();
    for (int off = 1; off < 256; off <<= 1) {
        int t = (tid >= off) ? lscan[tid - off] : 0;
        __syncthreads();
        lscan[tid] += t;
        __syncthreads();
    }
    int excl = lscan[tid] - c;
    lcur[tid] = excl;

    int g = (b << BKT_SHIFT) + tid;
    if (g < N) { rbeg[g] = base + excl; rend[g] = base + excl + c; }
    __syncthreads();

    for (int i = tid; i < n; i += 256) {
        int2 rec = staged_g[base + i];
        int tl = (rec.x >> 17) & (BKT_SIZE - 1);
        int pos = atomicAdd(&lcur[tl], 1);
        sorted_sp[base + pos] = make_int2(rec.x & 0x1FFFF, rec.y);
    }
}

// ---------------------------------------------------------------------------
// Kernel 4: segmented reduction (R0's proven 42.6us kernel). One wave per
// target; 8 sub-groups of 8 lanes, each sub owns one edge per iteration;
// each lane loads ushort8 (16 B). 25,000 blocks -> latency fully hidden.
// ---------------------------------------------------------------------------
__global__ __launch_bounds__(256) void gat_aggregate_csr(
    const int* __restrict__ rbeg, const int* __restrict__ rend,
    const int2* __restrict__ sorted_sp,
    const unsigned short* __restrict__ Wh, float* __restrict__ out, int N)
{
    int t = blockIdx.x * 4 + (threadIdx.x >> 6);
    if (t >= N) return;
    int lane = threadIdx.x & 63;
    int sub  = lane >> 3;    // edge slot 0..7
    int c8   = lane & 7;     // channel block: channels c8*8 .. c8*8+7

    int beg = rbeg[t], end = rend[t];

    float acc[8] = {0.f, 0.f, 0.f, 0.f, 0.f, 0.f, 0.f, 0.f};
    float psum = 0.f;

    int i = beg + sub;
    for (; i + 8 < end; i += 16) {
        int2 spA = sorted_sp[i];
        int2 spB = sorted_sp[i + 8];
        float pA = __int_as_float(spA.y);
        float pB = __int_as_float(spB.y);
        ushortx8 wA = *(const ushortx8*)&Wh[(size_t)spA.x * DOUT + c8 * 8];
        ushortx8 wB = *(const ushortx8*)&Wh[(size_t)spB.x * DOUT + c8 * 8];
        #pragma unroll
        for (int j = 0; j < 8; ++j) acc[j] += pA * bf16_to_f32(wA[j]);
        psum += pA;
        #pragma unroll
        for (int j = 0; j < 8; ++j) acc[j] += pB * bf16_to_f32(wB[j]);
        psum += pB;
    }
    if (i < end) {
        int2 sp = sorted_sp[i];
        float p = __int_as_float(sp.y);
        ushortx8 w = *(const ushortx8*)&Wh[(size_t)sp.x * DOUT + c8 * 8];
        #pragma unroll
        for (int j = 0; j < 8; ++j) acc[j] += p * bf16_to_f32(w[j]);
        psum += p;
    }

    #pragma unroll
    for (int m = 8; m < 64; m <<= 1) {
        #pragma unroll
        for (int j = 0; j < 8; ++j) acc[j] += __shfl_xor(acc[j], m);
        psum += __shfl_xor(psum, m);
    }

    if (sub == 0) {
        float inv = 1.0f / (psum + EPSV);
        float4 o0 = make_float4(acc[0] * inv, acc[1] * inv, acc[2] * inv, acc[3] * inv);
        float4 o1 = make_float4(acc[4] * inv, acc[5] * inv, acc[6] * inv, acc[7] * inv);
        *(float4*)&out[(size_t)t * DOUT + c8 * 8]     = o0;
        *(float4*)&out[(size_t)t * DOUT + c8 * 8 + 4] = o1;
    }
}

extern "C" void kernel_launch(void* const* d_in, const int* in_sizes, int n_in,
                              void* d_out, int out_size, void* d_ws, size_t ws_size,
                              hipStream_t stream) {
    const float* x  = (const float*)d_in[0];
    const int*   ei = (const int*)d_in[1];
    const float* ew = (const float*)d_in[2];
    const float* W  = (const float*)d_in[3];
    const float* a  = (const float*)d_in[4];
    const int N = in_sizes[0] / DIN;
    const int E = in_sizes[2];
    float* out = (float*)d_out;

    const int nbk = (N + BKT_SIZE - 1) >> BKT_SHIFT;   // 391

    char* wsb = (char*)d_ws;
    unsigned short* Wh = (unsigned short*)wsb;      wsb += (size_t)N * DOUT * 2;
    float* ssrc      = (float*)wsb;                 wsb += (size_t)N * 4;
    float* stgt      = (float*)wsb;                 wsb += (size_t)N * 4;
    int*   rbeg      = (int*)wsb;                   wsb += (size_t)N * 4;
    int*   rend      = (int*)wsb;                   wsb += (size_t)N * 4;
    int*   cnt       = (int*)wsb;                   wsb += NBMAX * 4;
    wsb = (char*)(((uintptr_t)wsb + 15) & ~(uintptr_t)15);
    int2*  staged_g  = (int2*)wsb;                  wsb += (size_t)nbk * CAP_B * 8;
    int2*  sorted_sp = (int2*)wsb;                  wsb += (size_t)nbk * CAP_B * 8;

    (void)hipMemsetAsync(cnt, 0, NBMAX * sizeof(int), stream);

    gat_gemm_scores<<<(N + 63) / 64, 256, 0, stream>>>(x, W, a, Wh, ssrc, stgt, N);
    gat_bin_fused<<<(E + PASSA_CHUNK - 1) / PASSA_CHUNK, 256, 0, stream>>>(
                  ei, ew, ssrc, stgt, cnt, staged_g, E);
    gat_binB_sort<<<nbk, 256, 0, stream>>>(staged_g, cnt, rbeg, rend, sorted_sp, N);
    gat_aggregate_csr<<<(N + 3) / 4, 256, 0, stream>>>(rbeg, rend, sorted_sp, Wh, out, N);
}